// Round 6
// baseline (147.432 us; speedup 1.0000x reference)
//
#include <hip/hip_runtime.h>
#include <math.h>

// B=16,H=14,W=14,D=512, L=32, HID=512, A=512. fp32 in/out; bf16 internal for GEMMs.
#define Bn   16
#define Ln   32
#define Pn   196
#define BLn  512

typedef __attribute__((ext_vector_type(8))) short short8;
typedef __attribute__((ext_vector_type(4))) float f32x4;

__device__ __forceinline__ unsigned short f2bf(float x) {
    union { float f; unsigned u; } c; c.f = x;
    const unsigned r = c.u + 0x7FFFu + ((c.u >> 16) & 1u);   // RNE (inputs finite)
    return (unsigned short)(r >> 16);
}

// ---------------- K0: fp32 -> bf16 for hiddens, W_hidden, W_co ----------------
__global__ __launch_bounds__(256) void convert_kernel(
    const float* __restrict__ s0, const float* __restrict__ s1, const float* __restrict__ s2,
    unsigned short* __restrict__ d0, unsigned short* __restrict__ d1, unsigned short* __restrict__ d2)
{
    const float* s = (blockIdx.y == 0) ? s0 : (blockIdx.y == 1) ? s1 : s2;
    unsigned short* d = (blockIdx.y == 0) ? d0 : (blockIdx.y == 1) ? d1 : d2;
    const int i = blockIdx.x * 256 + threadIdx.x;          // 65536 float4 per array
    const float4 v = ((const float4*)s)[i];
    ushort4 o;
    o.x = f2bf(v.x); o.y = f2bf(v.y); o.z = f2bf(v.z); o.w = f2bf(v.w);
    ((ushort4*)d)[i] = o;
}

// ---------------- K1/K4: MFMA GEMM  C = A(M,K)_bf16 · B(N,K)_bf16^T (+bias[n]) [*hmul] ----
// M=N=K=512. 32x32 tile per 64-thread block, grid 16x16. Fragment-order LDS staging:
// slot (2s+t)*64+lane holds A[m0+16t+(lane&15)][32s+(lane>>4)*8 ..+7] -> ds_read_b128
// at wave-base+lane*16 (conflict-free), MFMA 16x16x32, fp32 accum.
template<int MODE>
__global__ __launch_bounds__(64) void mfma_gemm_nt(
    const unsigned short* __restrict__ A, const unsigned short* __restrict__ B,
    const float* __restrict__ bias, const float* __restrict__ hmul,
    float* __restrict__ C)
{
    const int m0 = blockIdx.x * 32, n0 = blockIdx.y * 32;
    const int lane = threadIdx.x;
    __shared__ uint4 As[2048];
    __shared__ uint4 Bs[2048];

    const int quad = lane >> 4, mp = lane & 15;
    #pragma unroll 4
    for (int i = 0; i < 32; ++i) {
        const int t = i & 1, s = i >> 1;
        const int row  = t * 16 + mp;
        const int col8 = s * 4 + quad;                     // uint4 (8 bf16) index in row
        As[i * 64 + lane] = *(const uint4*)(A + (size_t)(m0 + row) * 512 + col8 * 8);
        Bs[i * 64 + lane] = *(const uint4*)(B + (size_t)(n0 + row) * 512 + col8 * 8);
    }
    __syncthreads();

    f32x4 acc00 = {0.f,0.f,0.f,0.f};
    f32x4 acc01 = acc00, acc10 = acc00, acc11 = acc00;
    #pragma unroll
    for (int s = 0; s < 16; ++s) {
        const short8 a0 = *reinterpret_cast<const short8*>(&As[(2*s+0)*64 + lane]);
        const short8 a1 = *reinterpret_cast<const short8*>(&As[(2*s+1)*64 + lane]);
        const short8 b0 = *reinterpret_cast<const short8*>(&Bs[(2*s+0)*64 + lane]);
        const short8 b1 = *reinterpret_cast<const short8*>(&Bs[(2*s+1)*64 + lane]);
        acc00 = __builtin_amdgcn_mfma_f32_16x16x32_bf16(a0, b0, acc00, 0, 0, 0);
        acc01 = __builtin_amdgcn_mfma_f32_16x16x32_bf16(a0, b1, acc01, 0, 0, 0);
        acc10 = __builtin_amdgcn_mfma_f32_16x16x32_bf16(a1, b0, acc10, 0, 0, 0);
        acc11 = __builtin_amdgcn_mfma_f32_16x16x32_bf16(a1, b1, acc11, 0, 0, 0);
    }

    // C/D layout: col = lane&15, row = (lane>>4)*4 + reg  [m89-verified]
    const int row4 = quad * 4, col = mp;
    const f32x4 accs[2][2] = { {acc00, acc01}, {acc10, acc11} };
    #pragma unroll
    for (int tm = 0; tm < 2; ++tm)
        #pragma unroll
        for (int tn = 0; tn < 2; ++tn)
            #pragma unroll
            for (int r = 0; r < 4; ++r) {
                const int m = m0 + tm*16 + row4 + r, n = n0 + tn*16 + col;
                float v = accs[tm][tn][r] + bias[n];
                if (MODE == 1) v *= hmul[(size_t)m*512 + n];
                C[(size_t)m*512 + n] = v;
            }
}

// ---------------- K2: raw scores ----------------
// grid (16 b, 14 ptiles), 256 thr: kc = tid>>4 owns cols {j4*64+kc*4+e}; lgrp=tid&15 owns
// l = 2*lgrp, 2*lgrp+1. W_rect/hlin in registers (global L2); only fmaps in LDS.
__global__ __launch_bounds__(256) void scores_kernel(
    const float* __restrict__ maps, const float* __restrict__ hlin,
    const float* __restrict__ W_rect, const float* __restrict__ b_rect,
    float* __restrict__ scores_out)
{
    const int b = blockIdx.x, p0 = blockIdx.y * 14;
    const int tid = threadIdx.x;
    const int kc = tid >> 4, lgrp = tid & 15, l0 = lgrp * 2;

    __shared__ float fls[14][516];
    __shared__ float red[4][14][32];

    const float* fbase = maps + ((size_t)b * Pn + p0) * 512;
    #pragma unroll
    for (int i = 0; i < 7; ++i) {                          // 14*512/4 = 1792 float4
        const int fidx = i * 256 + tid;
        const int e = fidx * 4, p = e >> 9, c = e & 511;
        *(float4*)&fls[p][c] = *(const float4*)(fbase + (size_t)p * 512 + c);
    }

    float4 wreg[8], hregA[8], hregB[8];
    const int colbase = kc * 4;
    const float* h0 = hlin + ((size_t)b * 32 + l0) * 512;
    #pragma unroll
    for (int j4 = 0; j4 < 8; ++j4) {
        const int c = j4 * 64 + colbase;
        wreg[j4]  = *(const float4*)(W_rect + c);
        hregA[j4] = *(const float4*)(h0 + c);
        hregB[j4] = *(const float4*)(h0 + 512 + c);
    }
    __syncthreads();

    float acc[14][2];
    #pragma unroll
    for (int p = 0; p < 14; ++p) { acc[p][0] = 0.f; acc[p][1] = 0.f; }

    #pragma unroll
    for (int j4 = 0; j4 < 8; ++j4) {
        const int c = j4 * 64 + colbase;
        const float4 w4 = wreg[j4], hA = hregA[j4], hB = hregB[j4];
        #pragma unroll
        for (int p = 0; p < 14; ++p) {
            const float4 f4 = *(const float4*)&fls[p][c];
            acc[p][0] += fmaxf(f4.x + hA.x, 0.f) * w4.x + fmaxf(f4.y + hA.y, 0.f) * w4.y
                       + fmaxf(f4.z + hA.z, 0.f) * w4.z + fmaxf(f4.w + hA.w, 0.f) * w4.w;
            acc[p][1] += fmaxf(f4.x + hB.x, 0.f) * w4.x + fmaxf(f4.y + hB.y, 0.f) * w4.y
                       + fmaxf(f4.z + hB.z, 0.f) * w4.z + fmaxf(f4.w + hB.w, 0.f) * w4.w;
        }
    }

    // reduce over the wave's 4 kc (lanes l, l+16, l+32, l+48 share lgrp)
    #pragma unroll
    for (int p = 0; p < 14; ++p)
        #pragma unroll
        for (int s = 0; s < 2; ++s) {
            float v = acc[p][s];
            v += __shfl_down(v, 32);
            v += __shfl_down(v, 16);
            acc[p][s] = v;
        }
    const int wave = tid >> 6, lane = tid & 63;
    if (lane < 16) {
        #pragma unroll
        for (int p = 0; p < 14; ++p) {
            red[wave][p][l0]     = acc[p][0];
            red[wave][p][l0 + 1] = acc[p][1];
        }
    }
    __syncthreads();

    const float br = b_rect[0];
    const int l2 = tid & 31, pb = tid >> 5;
    for (int pp = pb; pp < 14; pp += 8) {
        const float s = red[0][pp][l2] + red[1][pp][l2] + red[2][pp][l2] + red[3][pp][l2] + br;
        scores_out[((size_t)b * 32 + l2) * Pn + p0 + pp] = s;
    }
}

// ---------------- K3: softmax + ctx (bf16 out) ----------------
// grid (16 b, 16 dtiles of 32), 256 thr. blockIdx.y==0 also writes normalized attn.
__global__ __launch_bounds__(256) void softmax_ctx_kernel(
    const float* __restrict__ maps, const float* __restrict__ scores,
    float* __restrict__ attn_out, unsigned short* __restrict__ ctx_out)
{
    const int b = blockIdx.x, d0 = blockIdx.y * 32;
    const int tid = threadIdx.x;
    __shared__ float ft[196][36];
    __shared__ float at[32][204];

    const float* fbase = maps + (size_t)b * Pn * 512 + d0;
    for (int fidx = tid; fidx < 1568; fidx += 256) {       // 196*32/4
        const int p = fidx >> 3, q = fidx & 7;
        *(float4*)&ft[p][q * 4] = *(const float4*)(fbase + (size_t)p * 512 + q * 4);
    }
    const float* sbase = scores + (size_t)b * 32 * Pn;
    for (int idx = tid; idx < 32 * Pn; idx += 256) {
        const int r = idx / Pn;
        at[r][idx - r * Pn] = sbase[idx];
    }
    __syncthreads();

    // softmax per row; 4 waves x 8 rows
    const int wave = tid >> 6, lane = tid & 63;
    #pragma unroll
    for (int rr = 0; rr < 8; ++rr) {
        const int row = wave * 8 + rr;
        float v[4];
        #pragma unroll
        for (int i = 0; i < 4; ++i) {
            const int p = lane + 64 * i;
            v[i] = (p < Pn) ? at[row][p] : -INFINITY;
        }
        float m = fmaxf(fmaxf(v[0], v[1]), fmaxf(v[2], v[3]));
        for (int off = 32; off > 0; off >>= 1) m = fmaxf(m, __shfl_down(m, off));
        m = __shfl(m, 0);
        float e[4], s = 0.f;
        #pragma unroll
        for (int i = 0; i < 4; ++i) {
            const int p = lane + 64 * i;
            e[i] = (p < Pn) ? __expf(v[i] - m) : 0.f;
            s += e[i];
        }
        for (int off = 32; off > 0; off >>= 1) s += __shfl_down(s, off);
        s = __shfl(s, 0);
        const float inv = 1.f / s;
        #pragma unroll
        for (int i = 0; i < 4; ++i) {
            const int p = lane + 64 * i;
            if (p < Pn) at[row][p] = e[i] * inv;
        }
    }
    __syncthreads();

    if (blockIdx.y == 0) {
        for (int idx = tid; idx < 32 * Pn; idx += 256) {
            const int r = idx / Pn;
            attn_out[(size_t)b * 32 * Pn + idx] = at[r][idx - r * Pn];
        }
    }

    // ctx[l][d0+d4*4 ..+3] = sum_p at[l][p] * ft[p][...]
    const int l = tid >> 3, d4 = tid & 7;
    float ax = 0.f, ay = 0.f, az = 0.f, aw = 0.f;
    for (int p4 = 0; p4 < 49; ++p4) {
        const float4 a4 = *(const float4*)&at[l][p4 * 4];
        const float4 f0 = *(const float4*)&ft[p4 * 4 + 0][d4 * 4];
        const float4 f1 = *(const float4*)&ft[p4 * 4 + 1][d4 * 4];
        const float4 f2 = *(const float4*)&ft[p4 * 4 + 2][d4 * 4];
        const float4 f3 = *(const float4*)&ft[p4 * 4 + 3][d4 * 4];
        ax += a4.x * f0.x + a4.y * f1.x + a4.z * f2.x + a4.w * f3.x;
        ay += a4.x * f0.y + a4.y * f1.y + a4.z * f2.y + a4.w * f3.y;
        az += a4.x * f0.z + a4.y * f1.z + a4.z * f2.z + a4.w * f3.z;
        aw += a4.x * f0.w + a4.y * f1.w + a4.z * f2.w + a4.w * f3.w;
    }
    ushort4 o;
    o.x = f2bf(ax); o.y = f2bf(ay); o.z = f2bf(az); o.w = f2bf(aw);
    *(ushort4*)(ctx_out + ((size_t)b * 32 + l) * 512 + d0 + d4 * 4) = o;
}

extern "C" void kernel_launch(void* const* d_in, const int* in_sizes, int n_in,
                              void* d_out, int out_size, void* d_ws, size_t ws_size,
                              hipStream_t stream)
{
    const float* maps     = (const float*)d_in[0];
    const float* hiddens  = (const float*)d_in[1];
    const float* W_hidden = (const float*)d_in[2];
    const float* b_hidden = (const float*)d_in[3];
    const float* W_rect   = (const float*)d_in[4];
    const float* b_rect   = (const float*)d_in[5];
    const float* W_co     = (const float*)d_in[6];
    const float* b_co     = (const float*)d_in[7];

    float* out_co   = (float*)d_out;                     // (512,512): hlin, then final
    float* out_attn = out_co + (size_t)BLn * 512;        // (512,196)

    char* ws = (char*)d_ws;
    float*          scores = (float*)(ws);                            // 512*196*4  < 512K
    unsigned short* hb16   = (unsigned short*)(ws + (512 << 10));     // 512K
    unsigned short* whb16  = (unsigned short*)(ws + (1024 << 10));    // 512K
    unsigned short* wcob16 = (unsigned short*)(ws + (1536 << 10));    // 512K
    unsigned short* ctx16  = (unsigned short*)(ws + (2048 << 10));    // 512K

    hipLaunchKernelGGL(convert_kernel, dim3(256, 3), dim3(256), 0, stream,
                       hiddens, W_hidden, W_co, hb16, whb16, wcob16);
    hipLaunchKernelGGL((mfma_gemm_nt<0>), dim3(16, 16), dim3(64), 0, stream,
                       hb16, whb16, b_hidden, (const float*)nullptr, out_co);
    hipLaunchKernelGGL(scores_kernel, dim3(Bn, 14), dim3(256), 0, stream,
                       maps, out_co, W_rect, b_rect, scores);
    hipLaunchKernelGGL(softmax_ctx_kernel, dim3(Bn, 16), dim3(256), 0, stream,
                       maps, scores, out_attn, ctx16);
    hipLaunchKernelGGL((mfma_gemm_nt<1>), dim3(16, 16), dim3(64), 0, stream,
                       ctx16, wcob16, b_co, hiddens, out_co);
}

// Round 7
// 111.453 us; speedup vs baseline: 1.3228x; 1.3228x over previous
//
#include <hip/hip_runtime.h>
#include <math.h>

// B=16,H=14,W=14,D=512, L=32, HID=512, A=512. fp32 in/out; bf16 inside MFMA GEMMs.
#define Bn   16
#define Ln   32
#define Pn   196
#define BLn  512

typedef __attribute__((ext_vector_type(8))) short short8;
typedef __attribute__((ext_vector_type(4))) float f32x4;

__device__ __forceinline__ unsigned f2bf_u(float x) {
    union { float f; unsigned u; } c; c.f = x;
    return (c.u + 0x7FFFu + ((c.u >> 16) & 1u)) >> 16;   // RNE, finite inputs
}
__device__ __forceinline__ unsigned short f2bf(float x) { return (unsigned short)f2bf_u(x); }
__device__ __forceinline__ unsigned pack2(float lo, float hi) {
    return f2bf_u(lo) | (f2bf_u(hi) << 16);
}
__device__ __forceinline__ uint4 pack8(const float4 a, const float4 b) {
    uint4 r;
    r.x = pack2(a.x, a.y); r.y = pack2(a.z, a.w);
    r.z = pack2(b.x, b.y); r.w = pack2(b.z, b.w);
    return r;
}

// ---------------- K1/K4: MFMA GEMM  C = A(M,K) · B(N,K)^T + bias[n] [*hmul] ------------
// M=N=K=512. 32x32 tile per 64-thread block, grid 16x16. fp32 inputs are converted to
// bf16 during LDS staging (MODE 0: A fp32; MODE 1: A already bf16 = ctx16, *hmul epilogue).
// LDS slot (2s+t)*64+lane holds A[m0+16t+(lane&15)][32s+(lane>>4)*8 ..+7] -> ds_read_b128
// at wave-base+lane*16 (conflict-free). MFMA 16x16x32 bf16, fp32 accum.
template<int MODE>
__global__ __launch_bounds__(64) void mfma_gemm(
    const float* __restrict__ Af, const unsigned short* __restrict__ Ab,
    const float* __restrict__ B, const float* __restrict__ bias,
    const float* __restrict__ hmul, float* __restrict__ C)
{
    const int m0 = blockIdx.x * 32, n0 = blockIdx.y * 32;
    const int lane = threadIdx.x;
    __shared__ uint4 As[2048];
    __shared__ uint4 Bs[2048];

    const int quad = lane >> 4, mp = lane & 15;
    #pragma unroll 4
    for (int i = 0; i < 32; ++i) {
        const int t = i & 1, s = i >> 1;
        const int row  = t * 16 + mp;
        const int col8 = s * 4 + quad;                    // 8-elem group index within row
        uint4 av;
        if (MODE == 0) {
            const float* ap = Af + (size_t)(m0 + row) * 512 + col8 * 8;
            av = pack8(*(const float4*)ap, *(const float4*)(ap + 4));
        } else {
            av = *(const uint4*)(Ab + (size_t)(m0 + row) * 512 + col8 * 8);
        }
        const float* bp = B + (size_t)(n0 + row) * 512 + col8 * 8;
        As[i * 64 + lane] = av;
        Bs[i * 64 + lane] = pack8(*(const float4*)bp, *(const float4*)(bp + 4));
    }
    __syncthreads();

    f32x4 acc00 = {0.f,0.f,0.f,0.f};
    f32x4 acc01 = acc00, acc10 = acc00, acc11 = acc00;
    #pragma unroll
    for (int s = 0; s < 16; ++s) {
        const short8 a0 = *reinterpret_cast<const short8*>(&As[(2*s+0)*64 + lane]);
        const short8 a1 = *reinterpret_cast<const short8*>(&As[(2*s+1)*64 + lane]);
        const short8 b0 = *reinterpret_cast<const short8*>(&Bs[(2*s+0)*64 + lane]);
        const short8 b1 = *reinterpret_cast<const short8*>(&Bs[(2*s+1)*64 + lane]);
        acc00 = __builtin_amdgcn_mfma_f32_16x16x32_bf16(a0, b0, acc00, 0, 0, 0);
        acc01 = __builtin_amdgcn_mfma_f32_16x16x32_bf16(a0, b1, acc01, 0, 0, 0);
        acc10 = __builtin_amdgcn_mfma_f32_16x16x32_bf16(a1, b0, acc10, 0, 0, 0);
        acc11 = __builtin_amdgcn_mfma_f32_16x16x32_bf16(a1, b1, acc11, 0, 0, 0);
    }

    // C/D layout: col = lane&15, row = (lane>>4)*4 + reg  [m89-verified]
    const int row4 = quad * 4, col = mp;
    const f32x4 accs[2][2] = { {acc00, acc01}, {acc10, acc11} };
    #pragma unroll
    for (int tm = 0; tm < 2; ++tm)
        #pragma unroll
        for (int tn = 0; tn < 2; ++tn)
            #pragma unroll
            for (int r = 0; r < 4; ++r) {
                const int m = m0 + tm*16 + row4 + r, n = n0 + tn*16 + col;
                float v = accs[tm][tn][r] + bias[n];
                if (MODE == 1) v *= hmul[(size_t)m*512 + n];
                C[(size_t)m*512 + n] = v;
            }
}

// ---------------- K2: raw scores (R5 LDS-resident form) ----------------
// grid (16 b, 14 ptiles), 256 threads: tid = kc*32 + l (kc: a-chunk of 64, l: 0..31)
__global__ __launch_bounds__(256) void scores_kernel(
    const float* __restrict__ maps, const float* __restrict__ hlin,
    const float* __restrict__ W_rect, const float* __restrict__ b_rect,
    float* __restrict__ scores_out)
{
    const int b = blockIdx.x, p0 = blockIdx.y * 14;
    const int tid = threadIdx.x;
    const int kc = tid >> 5, l = tid & 31;

    __shared__ float fls[14][516];     // fmaps tile
    __shared__ float hls[32][516];     // hlin rows for this b
    __shared__ float wls[516];
    __shared__ float red[4][14][32];

    const float* fbase = maps + ((size_t)b * Pn + p0) * 512;
    #pragma unroll
    for (int i = 0; i < 7; ++i) {                       // 14*512/4 = 1792 float4
        const int fidx = i * 256 + tid;
        const int e = fidx * 4, p = e >> 9, c = e & 511;
        *(float4*)&fls[p][c] = *(const float4*)(fbase + (size_t)p * 512 + c);
    }
    const float* hbase = hlin + (size_t)b * 32 * 512;
    #pragma unroll
    for (int i = 0; i < 16; ++i) {                      // 32*512/4 = 4096 float4
        const int fidx = i * 256 + tid;
        const int e = fidx * 4, r = e >> 9, c = e & 511;
        *(float4*)&hls[r][c] = *(const float4*)(hbase + (size_t)r * 512 + c);
    }
    if (tid < 128)
        *(float4*)&wls[tid * 4] = *(const float4*)(W_rect + tid * 4);
    __syncthreads();

    float acc[14];
    #pragma unroll
    for (int p = 0; p < 14; ++p) acc[p] = 0.f;

    const int off = kc * 64;
    for (int j4 = 0; j4 < 16; ++j4) {
        const float4 w4 = *(const float4*)&wls[off + j4 * 4];
        const float4 h4 = *(const float4*)&hls[l][off + j4 * 4];
        #pragma unroll
        for (int p = 0; p < 14; ++p) {
            const float4 f4 = *(const float4*)&fls[p][off + j4 * 4];
            acc[p] += fmaxf(f4.x + h4.x, 0.f) * w4.x + fmaxf(f4.y + h4.y, 0.f) * w4.y
                    + fmaxf(f4.z + h4.z, 0.f) * w4.z + fmaxf(f4.w + h4.w, 0.f) * w4.w;
        }
    }

    // reduce over kc: pair within wave (kc, kc+1 are lanes l and l+32)
    #pragma unroll
    for (int p = 0; p < 14; ++p) acc[p] += __shfl_down(acc[p], 32);
    const int wave = tid >> 6;
    if ((tid & 63) < 32) {
        #pragma unroll
        for (int p = 0; p < 14; ++p) red[wave][p][l] = acc[p];
    }
    __syncthreads();

    const float br = b_rect[0];
    const int l2 = tid & 31, pb = tid >> 5;   // pb 0..7
    for (int pp = pb; pp < 14; pp += 8) {
        const float s = red[0][pp][l2] + red[1][pp][l2] + red[2][pp][l2] + red[3][pp][l2] + br;
        scores_out[((size_t)b * 32 + l2) * Pn + p0 + pp] = s;
    }
}

// ---------------- K3: softmax + ctx (bf16 out) ----------------
// grid (16 b, 16 dtiles of 32), 256 thr. blockIdx.y==0 also writes normalized attn.
__global__ __launch_bounds__(256) void softmax_ctx_kernel(
    const float* __restrict__ maps, const float* __restrict__ scores,
    float* __restrict__ attn_out, unsigned short* __restrict__ ctx_out)
{
    const int b = blockIdx.x, d0 = blockIdx.y * 32;
    const int tid = threadIdx.x;
    __shared__ float ft[196][36];
    __shared__ float at[32][204];

    const float* fbase = maps + (size_t)b * Pn * 512 + d0;
    for (int fidx = tid; fidx < 1568; fidx += 256) {       // 196*32/4
        const int p = fidx >> 3, q = fidx & 7;
        *(float4*)&ft[p][q * 4] = *(const float4*)(fbase + (size_t)p * 512 + q * 4);
    }
    const float4* sbase4 = (const float4*)(scores + (size_t)b * 32 * Pn);
    for (int fidx = tid; fidx < 1568; fidx += 256) {       // 32 rows x 49 float4
        const int r = fidx / 49, c4 = fidx - r * 49;
        *(float4*)&at[r][c4 * 4] = sbase4[fidx];
    }
    __syncthreads();

    // softmax per row; 4 waves x 8 rows
    const int wave = tid >> 6, lane = tid & 63;
    #pragma unroll
    for (int rr = 0; rr < 8; ++rr) {
        const int row = wave * 8 + rr;
        float v[4];
        #pragma unroll
        for (int i = 0; i < 4; ++i) {
            const int p = lane + 64 * i;
            v[i] = (p < Pn) ? at[row][p] : -INFINITY;
        }
        float m = fmaxf(fmaxf(v[0], v[1]), fmaxf(v[2], v[3]));
        for (int off = 32; off > 0; off >>= 1) m = fmaxf(m, __shfl_down(m, off));
        m = __shfl(m, 0);
        float e[4], s = 0.f;
        #pragma unroll
        for (int i = 0; i < 4; ++i) {
            const int p = lane + 64 * i;
            e[i] = (p < Pn) ? __expf(v[i] - m) : 0.f;
            s += e[i];
        }
        for (int off = 32; off > 0; off >>= 1) s += __shfl_down(s, off);
        s = __shfl(s, 0);
        const float inv = 1.f / s;
        #pragma unroll
        for (int i = 0; i < 4; ++i) {
            const int p = lane + 64 * i;
            if (p < Pn) at[row][p] = e[i] * inv;
        }
    }
    __syncthreads();

    if (blockIdx.y == 0) {
        float4* ao4 = (float4*)(attn_out + (size_t)b * 32 * Pn);
        for (int fidx = tid; fidx < 1568; fidx += 256) {
            const int r = fidx / 49, c4 = fidx - r * 49;
            ao4[fidx] = *(const float4*)&at[r][c4 * 4];
        }
    }

    // ctx[l][d0+d4*4 ..+3] = sum_p at[l][p] * ft[p][...]
    const int l = tid >> 3, d4 = tid & 7;
    float ax = 0.f, ay = 0.f, az = 0.f, aw = 0.f;
    for (int p4 = 0; p4 < 49; ++p4) {
        const float4 a4 = *(const float4*)&at[l][p4 * 4];
        const float4 f0 = *(const float4*)&ft[p4 * 4 + 0][d4 * 4];
        const float4 f1 = *(const float4*)&ft[p4 * 4 + 1][d4 * 4];
        const float4 f2 = *(const float4*)&ft[p4 * 4 + 2][d4 * 4];
        const float4 f3 = *(const float4*)&ft[p4 * 4 + 3][d4 * 4];
        ax += a4.x * f0.x + a4.y * f1.x + a4.z * f2.x + a4.w * f3.x;
        ay += a4.x * f0.y + a4.y * f1.y + a4.z * f2.y + a4.w * f3.y;
        az += a4.x * f0.z + a4.y * f1.z + a4.z * f2.z + a4.w * f3.z;
        aw += a4.x * f0.w + a4.y * f1.w + a4.z * f2.w + a4.w * f3.w;
    }
    ushort4 o;
    o.x = f2bf(ax); o.y = f2bf(ay); o.z = f2bf(az); o.w = f2bf(aw);
    *(ushort4*)(ctx_out + ((size_t)b * 32 + l) * 512 + d0 + d4 * 4) = o;
}

extern "C" void kernel_launch(void* const* d_in, const int* in_sizes, int n_in,
                              void* d_out, int out_size, void* d_ws, size_t ws_size,
                              hipStream_t stream)
{
    const float* maps     = (const float*)d_in[0];
    const float* hiddens  = (const float*)d_in[1];
    const float* W_hidden = (const float*)d_in[2];
    const float* b_hidden = (const float*)d_in[3];
    const float* W_rect   = (const float*)d_in[4];
    const float* b_rect   = (const float*)d_in[5];
    const float* W_co     = (const float*)d_in[6];
    const float* b_co     = (const float*)d_in[7];

    float* out_co   = (float*)d_out;                     // (512,512): hlin, then final
    float* out_attn = out_co + (size_t)BLn * 512;        // (512,196)

    char* ws = (char*)d_ws;
    float*          scores = (float*)(ws);                          // 512*196*4 < 512K
    unsigned short* ctx16  = (unsigned short*)(ws + (512 << 10));   // 512K

    // 1) hlin = hiddens @ W_hidden^T + b_hidden  -> out_co  (bf16 MFMA, convert-in-staging)
    hipLaunchKernelGGL((mfma_gemm<0>), dim3(16, 16), dim3(64), 0, stream,
                       hiddens, (const unsigned short*)nullptr, W_hidden, b_hidden,
                       (const float*)nullptr, out_co);
    // 2) raw scores -> ws
    hipLaunchKernelGGL(scores_kernel, dim3(Bn, 14), dim3(256), 0, stream,
                       maps, out_co, W_rect, b_rect, scores);
    // 3) softmax (-> out_attn) + ctx (bf16 -> ws)
    hipLaunchKernelGGL(softmax_ctx_kernel, dim3(Bn, 16), dim3(256), 0, stream,
                       maps, scores, out_attn, ctx16);
    // 4) out_co = (ctx @ W_co^T + b_co) * hiddens  (bf16 MFMA, epilogue fused)
    hipLaunchKernelGGL((mfma_gemm<1>), dim3(16, 16), dim3(64), 0, stream,
                       (const float*)nullptr, ctx16, W_co, b_co, hiddens, out_co);
}